// Round 7
// baseline (497.951 us; speedup 1.0000x reference)
//
#include <hip/hip_runtime.h>
#include <math.h>

#define S 512
#define B 128
#define T 256
#define NTH 512
#define LOG2E 1.44269504f
#define LN2 0.69314718f

typedef _Float16 h2 __attribute__((ext_vector_type(2)));

#if __has_builtin(__builtin_amdgcn_fdot2)
#define FDOT2(a, b, c) __builtin_amdgcn_fdot2((a), (b), (c), false)
#else
#define FDOT2(a, b, c) fmaf((float)(a)[0], (float)(b)[0], fmaf((float)(a)[1], (float)(b)[1], (c)))
#endif

#if __has_builtin(__builtin_amdgcn_exp2f)
#define EXP2(x) __builtin_amdgcn_exp2f(x)
#else
#define EXP2(x) exp2f(x)
#endif
#if __has_builtin(__builtin_amdgcn_logf)
#define LOG2(x) __builtin_amdgcn_logf(x)
#else
#define LOG2(x) __log2f(x)
#endif

// cvt_pkrtz returns __fp16 vector; bit_cast to our h2
#define PKRTZ(a, b) __builtin_bit_cast(h2, __builtin_amdgcn_cvt_pkrtz((a), (b)))

#define AS1 __attribute__((address_space(1)))
#define AS3 __attribute__((address_space(3)))

// LDS-drain barrier only (DMA ring stays in flight; counted vmcnt elsewhere)
#define BAR() do { asm volatile("s_waitcnt lgkmcnt(0)" ::: "memory"); __builtin_amdgcn_s_barrier(); } while (0)

// exact x * 2^n (n in [-126,127])
__device__ __forceinline__ float mul2n(float x, int n) {
    return x * __builtin_bit_cast(float, (n + 127) << 23);
}

template<int CTRL, int RM>
__device__ __forceinline__ float dppmax(float x) {
    int xi = __builtin_bit_cast(int, x);
    int yi = __builtin_amdgcn_update_dpp(xi, xi, CTRL, RM, 0xf, false);
    return fmaxf(x, __builtin_bit_cast(float, yi));
}
__device__ __forceinline__ float wave_max64(float x) {
    x = dppmax<0x111, 0xf>(x);  // row_shr:1
    x = dppmax<0x112, 0xf>(x);  // row_shr:2
    x = dppmax<0x114, 0xf>(x);  // row_shr:4
    x = dppmax<0x118, 0xf>(x);  // row_shr:8
    x = dppmax<0x142, 0xa>(x);  // row_bcast:15
    x = dppmax<0x143, 0xc>(x);  // row_bcast:31
    return __builtin_bit_cast(float, __builtin_amdgcn_readlane(__builtin_bit_cast(int, x), 63));
}
// lane gets lane|1's value within each quad
__device__ __forceinline__ float quad_next(float x) {
    int xi = __builtin_bit_cast(int, x);
    int yi = __builtin_amdgcn_update_dpp(xi, xi, 0xF5, 0xf, 0xf, false);
    return __builtin_bit_cast(float, yi);
}

__global__ __launch_bounds__(NTH, 1) void crf_fwd(
    const float* __restrict__ feats,
    const int*   __restrict__ tags,
    const int*   __restrict__ mask,
    const float* __restrict__ start_t,
    const float* __restrict__ end_t,
    const float* __restrict__ trans,
    float*       __restrict__ out)
{
    const int tid  = threadIdx.x;
    const int inst = tid >> 8;        // 0/1: which batch element this half-block runs
    const int j    = tid & (T - 1);   // owned state column within instance
    const int lane = tid & 63;
    const int w4   = (tid >> 6) & 3;  // wave index within instance (GEMV rows [64w4,64w4+64))
    const int b    = 2 * blockIdx.x + inst;

    __shared__ float part[2][2][4][T];                            // [pp][inst][wave][col] 16 KB
    __shared__ float ftile[2][8][T];                              // [inst][slot][col] 16 KB ring
    __shared__ int   msk[2][S];                                   // 4 KB
    __shared__ __attribute__((aligned(16))) int Aex[2][2][4];     // [pp][inst][wave]
    __shared__ float redF[2][4], redS[2][4], redg[2][4], redm[2][4];

    // ---- prime DMA ring with feats tiles t=1..3 (each wave: uniform LDS base + lane*4)
    #pragma unroll
    for (int tn = 1; tn <= 3; ++tn) {
        const float* src = feats + ((size_t)tn * B + b) * T + j;
        __builtin_amdgcn_global_load_lds((const AS1 void*)src,
                                         (AS3 void*)&ftile[inst][tn][j], 4, 0, 0);
    }

    // ---- small per-thread loads
    const float endj = end_t[j];
    const float sc0  = start_t[j] + feats[(size_t)b * T + j];   // score at t=0
    msk[inst][j]     = mask[j * B + b];
    msk[inst][j + T] = mask[(j + T) * B + b];

    // ---- gold-score terms: two time steps per thread (256 threads x 2 = S)
    float gterm = 0.f, mcnt = 0.f;
    #pragma unroll
    for (int c = 0; c < 2; ++c) {
        const int t  = j + c * T;
        const int tg = tags[t * B + b];
        const int m  = mask[t * B + b];
        const float emit = feats[((size_t)t * B + b) * T + tg];
        mcnt += (float)m;
        if (t == 0) gterm += start_t[tg] + emit;
        else        gterm += m ? (emit + trans[tags[(t - 1) * B + b] * T + tg]) : 0.f;
    }
    #pragma unroll
    for (int o = 32; o > 0; o >>= 1) {
        gterm += __shfl_down(gterm, o, 64);
        mcnt  += __shfl_down(mcnt, o, 64);
    }
    if (lane == 0) { redg[inst][w4] = gterm; redm[inst][w4] = mcnt; }

    // ---- E fragment: rows i in [64w4, 64w4+64) paired, cols 4*lane..+3
    h2 E2[32][4];
    {
        const float* tp = trans + (size_t)(64 * w4) * T + 4 * lane;
        #pragma unroll
        for (int ip = 0; ip < 32; ++ip) {
            const float4 ra = *(const float4*)(tp + (size_t)(2 * ip) * T);
            const float4 rb = *(const float4*)(tp + (size_t)(2 * ip + 1) * T);
            #pragma unroll
            for (int c = 0; c < 4; ++c) {
                const float e0 = EXP2(LOG2E * (c == 0 ? ra.x : c == 1 ? ra.y : c == 2 ? ra.z : ra.w));
                const float e1 = EXP2(LOG2E * (c == 0 ? rb.x : c == 1 ? rb.y : c == 2 ? rb.z : rb.w));
                h2 v; v[0] = (_Float16)e0; v[1] = (_Float16)e1;
                E2[ip][c] = v;
            }
        }
    }

    // ---- linear-state init: q = 2^(sc0*log2e - A), per-wave A so wave max(q) ~= 2^-10
    float mq0 = wave_max64(sc0);
    int A = (int)ceilf(mq0 * LOG2E) + 10;
    float q = EXP2(fmaf(sc0, LOG2E, (float)(-A)));
    if (lane == 0) Aex[0][inst][w4] = A;
    float mq = wave_max64(q);
    int k = ((__builtin_bit_cast(int, mq) >> 23) & 0xff) - 117;   // exp(mq)-127+10
    int pki = __builtin_bit_cast(int, PKRTZ(q, quad_next(q)));

    __syncthreads();   // full drain once (init; primed tiles landed)

    float gold = 0.f;
    if (j == 0) {
        const float g  = redg[inst][0] + redg[inst][1] + redg[inst][2] + redg[inst][3];
        const float mc = redm[inst][0] + redm[inst][1] + redm[inst][2] + redm[inst][3];
        gold = g + end_t[tags[((int)mc - 1) * B + b]];
    }

    for (int t = 1; t < S; ++t) {
        // ---- GEMV over own wave's 64 rows (q pairs broadcast via readlane of own lanes)
        float a0 = 0.f, a1 = 0.f, a2 = 0.f, a3 = 0.f;
        int pr = __builtin_amdgcn_readlane(pki, 0);
        #pragma unroll
        for (int ip = 0; ip < 32; ++ip) {
            const int prn = (ip < 31) ? __builtin_amdgcn_readlane(pki, 2 * ip + 2) : 0;
            const h2 pp = __builtin_bit_cast(h2, pr);
            a0 = FDOT2(E2[ip][0], pp, a0);
            a1 = FDOT2(E2[ip][1], pp, a1);
            a2 = FDOT2(E2[ip][2], pp, a2);
            a3 = FDOT2(E2[ip][3], pp, a3);
            pr = prn;
        }
        {
            float4 acc; acc.x = a0; acc.y = a1; acc.z = a2; acc.w = a3;
            *(float4*)&part[t & 1][inst][w4][4 * lane] = acc;
        }
        // ---- DMA ring: prefetch tile t+3 (8-slot ring: no same-window rewrite)
        if (t < S - 3) {
            const float* src = feats + ((size_t)(t + 3) * B + b) * T + j;
            __builtin_amdgcn_global_load_lds((const AS1 void*)src,
                                             (AS3 void*)&ftile[inst][(t + 3) & 7][j], 4, 0, 0);
            asm volatile("s_waitcnt vmcnt(3)" ::: "memory");   // tile t landed
        } else {
            asm volatile("s_waitcnt vmcnt(0)" ::: "memory");
        }
        BAR();   // the only barrier per step

        // ---- combine: 4 partials with exact power-of-2 rescale (no log/exp of state)
        const int4  Av = *(const int4*)&Aex[(t - 1) & 1][inst][0];
        const float s0 = part[t & 1][inst][0][j];
        const float s1 = part[t & 1][inst][1][j];
        const float s2 = part[t & 1][inst][2][j];
        const float s3 = part[t & 1][inst][3][j];
        const float ft = ftile[inst][t & 7][j];
        const int mskt = msk[inst][t];
        const int a0i = __builtin_amdgcn_readfirstlane(Av.x);
        const int a1i = __builtin_amdgcn_readfirstlane(Av.y);
        const int a2i = __builtin_amdgcn_readfirstlane(Av.z);
        const int a3i = __builtin_amdgcn_readfirstlane(Av.w);
        const float cb = mul2n(s0, a0i - A) + mul2n(s1, a1i - A)
                       + mul2n(s2, a2i - A) + mul2n(s3, a3i - A);
        const float F  = EXP2(fmaf(ft, LOG2E, (float)(-k)));   // exp(ft)*2^-k
        const float qn = cb * F;
        const float qf = mul2n(q, -k);                          // frozen path (mask=0)
        q = mskt ? qn : qf;
        A += k;
        if (lane == 0) Aex[t & 1][inst][w4] = A;
        mq = wave_max64(q);                                     // for next step's k
        k = ((__builtin_bit_cast(int, mq) >> 23) & 0xff) - 117;
        pki = __builtin_bit_cast(int, PKRTZ(q, quad_next(q)));
    }

    BAR();

    // ---- finalize: score_j = (log2 q + A)*ln2; forward = LSE(score + end)
    const float u2 = LOG2(q) + (float)A + endj * LOG2E;
    {
        const float mw = wave_max64(u2);
        if (lane == 0) redF[inst][w4] = mw;
    }
    BAR();
    {
        const float gmax = fmaxf(fmaxf(redF[inst][0], redF[inst][1]),
                                 fmaxf(redF[inst][2], redF[inst][3]));
        float e = EXP2(u2 - gmax);
        #pragma unroll
        for (int o = 32; o > 0; o >>= 1) e += __shfl_xor(e, o, 64);
        if (lane == 0) redS[inst][w4] = e;
        BAR();
        if (j == 0) {
            const float ssum = redS[inst][0] + redS[inst][1] + redS[inst][2] + redS[inst][3];
            out[b] = (gmax + LOG2(ssum)) * LN2 - gold;
        }
    }
}

extern "C" void kernel_launch(void* const* d_in, const int* in_sizes, int n_in,
                              void* d_out, int out_size, void* d_ws, size_t ws_size,
                              hipStream_t stream) {
    const float* feats  = (const float*)d_in[0];
    const int*   tags   = (const int*)d_in[1];
    const int*   mask   = (const int*)d_in[2];
    const float* startt = (const float*)d_in[3];
    const float* endt   = (const float*)d_in[4];
    const float* transt = (const float*)d_in[5];
    float* out = (float*)d_out;
    crf_fwd<<<dim3(B / 2), dim3(NTH), 0, stream>>>(feats, tags, mask, startt, endt, transt, out);
}